// Round 5
// baseline (367.572 us; speedup 1.0000x reference)
//
#include <hip/hip_runtime.h>
#include <hip/hip_bf16.h>
#include <math.h>

// ---------------- types ----------------
typedef __bf16 bf16_t;
typedef __bf16 bf16x4 __attribute__((ext_vector_type(4)));
typedef __bf16 bf16x8 __attribute__((ext_vector_type(8)));
typedef float  f32x4  __attribute__((ext_vector_type(4)));

#define T_TOK 4096
#define H_DIM 1024
#define E_NUM 16
#define F_DIM 4096
#define CH_ROWS 128   // tokens per chunk-block (M tile)
#define CH_MAX  32    // max chunks per expert

// ---------------- workspace layout (bytes) ----------------
#define WS_E0     0            // int[4096]
#define WS_E1     16384        // int[4096]
#define WS_W0     32768        // float[4096]
#define WS_W1     49152        // float[4096]
#define WS_COUNTS 65536        // int[16]
#define WS_SUMW   65664        // float[16]
#define WS_XOFF   65792        // int[16]
#define WS_LIDX   131072       // int[16][4096]
#define WS_LW     393216       // float[16][4096]
#define WS_GPART  655360       // float[16][32][4096]  (8 MB)
#define WS_P2     655360       // float[512][1024] (2 MB) ALIASES gpart (dead after k_redg)
#define WS_G      9043968      // float[16][4096]
#define WS_XE     9306112      // bf16[80 rowblk][16 kt][128 row][64 k] (20 MB), tiled+swizzled
#define WS_W1T    30277632     // bf16 [g][32 ft][16 kt][128 f][64 k], up to 128 MB
#define W1T_PER_E 8388608      // 8 MB per expert

#define AS_GLOBAL(p) ((const __attribute__((address_space(1))) void*)(p))
#define AS_LDS(p)    ((__attribute__((address_space(3))) void*)(p))

// ---------------- kernel 1: routing (scores + top2 + softmax) ----------------
__global__ __launch_bounds__(64) void k_route(const float* __restrict__ x,
    const float* __restrict__ Wg, const float* __restrict__ bg,
    int* __restrict__ e0, int* __restrict__ e1,
    float* __restrict__ w0, float* __restrict__ w1)
{
    const int t = blockIdx.x;
    const int lane = threadIdx.x;
    const float* xr = x + (size_t)t * H_DIM;

    float s[E_NUM];
#pragma unroll
    for (int e = 0; e < E_NUM; ++e) s[e] = 0.f;

#pragma unroll
    for (int i = 0; i < 16; ++i) {
        const int h = i * 64 + lane;
        const float xv = xr[h];
        const float4* wr = (const float4*)(Wg + (size_t)h * E_NUM);
        float4 q0 = wr[0], q1 = wr[1], q2 = wr[2], q3 = wr[3];
        s[0] += xv*q0.x;  s[1] += xv*q0.y;  s[2] += xv*q0.z;  s[3] += xv*q0.w;
        s[4] += xv*q1.x;  s[5] += xv*q1.y;  s[6] += xv*q1.z;  s[7] += xv*q1.w;
        s[8] += xv*q2.x;  s[9] += xv*q2.y;  s[10]+= xv*q2.z;  s[11]+= xv*q2.w;
        s[12]+= xv*q3.x;  s[13]+= xv*q3.y;  s[14]+= xv*q3.z;  s[15]+= xv*q3.w;
    }
#pragma unroll
    for (int off = 32; off >= 1; off >>= 1) {
#pragma unroll
        for (int e = 0; e < E_NUM; ++e) s[e] += __shfl_xor(s[e], off);
    }
    if (lane == 0) {
#pragma unroll
        for (int e = 0; e < E_NUM; ++e) s[e] += bg[e];
        float b1v = -3e38f; int i1 = 0;
#pragma unroll
        for (int e = 0; e < E_NUM; ++e) { if (s[e] > b1v) { b1v = s[e]; i1 = e; } }
        float b2v = -3e38f; int i2 = 0;
#pragma unroll
        for (int e = 0; e < E_NUM; ++e) { if (e != i1 && s[e] > b2v) { b2v = s[e]; i2 = e; } }
        const float ex  = expf(b2v - b1v);
        const float inv = 1.f / (1.f + ex);
        e0[t] = i1; e1[t] = i2;
        w0[t] = inv; w1[t] = ex * inv;
    }
}

// ---------------- kernel 2: per-expert token lists ----------------
__global__ __launch_bounds__(64) void k_lists(const int* __restrict__ e0, const int* __restrict__ e1,
    const float* __restrict__ w0, const float* __restrict__ w1,
    int* __restrict__ lidx, float* __restrict__ lw,
    int* __restrict__ counts, float* __restrict__ sumw)
{
    const int e = blockIdx.x;
    const int lane = threadIdx.x;
    int cnt = 0; float sw = 0.f;
    for (int base = 0; base < T_TOK; base += 64) {
        const int t = base + lane;
        const bool m0 = (e0[t] == e);
        const bool m1 = (e1[t] == e);
        const bool m  = m0 | m1;
        const unsigned long long bal = __ballot(m);
        const int pos = cnt + __popcll(bal & ((1ull << lane) - 1ull));
        if (m) {
            const float w = m0 ? w0[t] : w1[t];
            lidx[e * T_TOK + pos] = t;
            lw[e * T_TOK + pos]   = w;
            sw += w;
        }
        cnt += __popcll(bal);
    }
#pragma unroll
    for (int off = 32; off >= 1; off >>= 1) sw += __shfl_xor(sw, off);
    if (lane == 0) { counts[e] = cnt; sumw[e] = sw; }
}

// ---------------- kernel 3: exclusive scan of 128-padded counts ----------------
__global__ void k_scan(const int* __restrict__ counts, int* __restrict__ xoff) {
    if (threadIdx.x == 0) {
        int o = 0;
        for (int e = 0; e < E_NUM; ++e) { xoff[e] = o; o += (counts[e] + CH_ROWS - 1) & ~(CH_ROWS - 1); }
    }
}

// ---------------- kernel 4: gather + f32->bf16 into TILED swizzled Xe ----------------
// Xe layout: [rowblk][kt 16][row 128][slot 8][8 elems]; slot s holds logical k-chunk
// s ^ (row&7). A K-step slab (16 KB) is fully contiguous -> linear global_load_lds.
__global__ __launch_bounds__(256) void k_gather(const float* __restrict__ x,
    const int* __restrict__ lidx, const int* __restrict__ counts,
    const int* __restrict__ xoff, bf16_t* __restrict__ Xe)
{
    const int chunk = blockIdx.x >> 1;
    const int part  = blockIdx.x & 1;
    const int e = blockIdx.y;
    const int cnt = counts[e];
    const int start = chunk * CH_ROWS;
    if (chunk && start >= cnt) return;
    const int tid = threadIdx.x;
    const size_t base = ((size_t)(xoff[e] >> 7) + chunk) * 131072;  // rowblk slab elems

    for (int it = 0; it < 32; ++it) {
        const int u    = part * 8192 + it * 256 + tid;  // 16384 16B-chunk tasks
        const int kt   = u >> 10;
        const int wi   = u & 1023;
        const int rl   = wi >> 3;       // 0..127 local row
        const int c    = wi & 7;        // storage slot
        const int row  = start + rl;
        bf16x8 v8 = {};
        if (row < cnt) {
            const int tok = lidx[e * T_TOK + row];
            const int cp  = c ^ (rl & 7);              // logical chunk
            const int k   = kt * 64 + cp * 8;
            const float4 a = *(const float4*)(x + (size_t)tok * H_DIM + k);
            const float4 b = *(const float4*)(x + (size_t)tok * H_DIM + k + 4);
            v8[0]=(bf16_t)a.x; v8[1]=(bf16_t)a.y; v8[2]=(bf16_t)a.z; v8[3]=(bf16_t)a.w;
            v8[4]=(bf16_t)b.x; v8[5]=(bf16_t)b.y; v8[6]=(bf16_t)b.z; v8[7]=(bf16_t)b.w;
        }
        *(bf16x8*)(Xe + base + (size_t)kt * 8192 + rl * 64 + c * 8) = v8;
    }
}

// ---------------- kernel 5: W1 tile-transpose + cvt -> W1T bf16 ----------------
// W1T layout: [ge][ft 32][kt 16][f 128][slot 8][8 k-elems], slot s = chunk s^(f&7).
// Block (kt, fq, ge): reads [64 k][1024 f] with 4KB-contiguous rows, LDS transpose,
// writes 8 ft-tiles of 16 KB contiguous.
__global__ __launch_bounds__(512, 1) void k_w1t(const float* __restrict__ W1,
    bf16_t* __restrict__ W1T, int ebase)
{
    const int kt = blockIdx.x;   // 0..15
    const int fq = blockIdx.y;   // 0..3
    const int ge = blockIdx.z;
    const int e  = ebase + ge;
    const int tid = threadIdx.x;

    __shared__ bf16_t S[64][1024];   // 128 KB

    const float* src = W1 + (size_t)e * H_DIM * F_DIM + (size_t)(kt * 64) * F_DIM + fq * 1024;
    // load: 64 rows x 256 float4 = 16384 tasks, 32 iters
    for (int it = 0; it < 32; ++it) {
        const int u   = it * 512 + tid;
        const int row = u >> 8;
        const int c4  = u & 255;
        const float4 v = *(const float4*)(src + (size_t)row * F_DIM + c4 * 4);
        bf16x4 b4; b4[0]=(bf16_t)v.x; b4[1]=(bf16_t)v.y; b4[2]=(bf16_t)v.z; b4[3]=(bf16_t)v.w;
        *(bf16x4*)&S[row][c4 * 4] = b4;
    }
    __syncthreads();

    // transpose out: 1024 output rows (8 ft x 128 f), 2 per thread
#pragma unroll
    for (int ot = 0; ot < 2; ++ot) {
        const int orow = ot * 512 + tid;
        const int ftl  = orow >> 7;      // 0..7
        const int f    = orow & 127;
        const int fg   = ftl * 128 + f;
        bf16_t kv[64];
#pragma unroll
        for (int k = 0; k < 64; ++k) kv[k] = S[k][fg];
        bf16_t* dst = W1T + ((((size_t)ge * 32 + (fq * 8 + ftl)) * 16 + kt) * 8192) + f * 64;
#pragma unroll
        for (int j = 0; j < 8; ++j) {
            bf16x8 pk;
#pragma unroll
            for (int q = 0; q < 8; ++q) pk[q] = kv[j * 8 + q];
            *(bf16x8*)&dst[((j ^ (f & 7)) * 8)] = pk;
        }
    }
}

// ---------------- kernel 6: expert GEMM (all-linear staging, 2-phase) ----------------
// grid: (32 ft, CH_MAX, g). block 256 = 4 waves (2M x 2N); wave tile 64x64; BK=64.
// A and B both staged with linear 16KB-slab global_load_lds from pre-swizzled buffers.
__global__ __launch_bounds__(256, 2) void k_expert(
    const bf16_t* __restrict__ W1T, const float* __restrict__ b1,
    const bf16_t* __restrict__ Xe, const float* __restrict__ lw,
    const int* __restrict__ counts, const int* __restrict__ xoff,
    float* __restrict__ gpart, int ebase)
{
    const int ftile = blockIdx.x;          // 0..31
    const int chunk = blockIdx.y;          // 0..31
    const int ge    = blockIdx.z;
    const int e     = ebase + ge;
    const int cnt   = counts[e];
    const int start = chunk * CH_ROWS;
    if (chunk && start >= cnt) return;

    __shared__ __align__(16) bf16_t Alds[2][8192];  // 2 x 16 KB
    __shared__ __align__(16) bf16_t Blds[2][8192];  // 2 x 16 KB
    __shared__ float w_s[CH_ROWS];
    __shared__ float b1_s[128];
    __shared__ float gred[2][128];

    const int tid  = threadIdx.x;
    const int lane = tid & 63;
    const int wid  = tid >> 6;      // 4 waves
    const int wm   = wid & 1;       // M half (64 rows)
    const int wn   = wid >> 1;      // N half (64 f)
    const int lr   = lane & 15;
    const int lg   = lane >> 4;

    if (tid < CH_ROWS) {
        const int r = start + tid;
        w_s[tid] = (r < cnt) ? lw[e * T_TOK + r] : 0.f;
    }
    if (tid < 128) b1_s[tid] = b1[(size_t)e * F_DIM + ftile * 128 + tid];

    f32x4 acc[4][4];
#pragma unroll
    for (int i = 0; i < 4; ++i)
#pragma unroll
        for (int j = 0; j < 4; ++j)
#pragma unroll
            for (int q = 0; q < 4; ++q) acc[i][j][q] = 0.f;

    const bf16_t* XeSlab = Xe + ((size_t)(xoff[e] >> 7) + chunk) * 131072;
    const bf16_t* W1Slab = W1T + (((size_t)ge * 32 + ftile) * 16) * 8192;

#define STAGE(T, BUF) { \
    const bf16_t* sa = XeSlab + (size_t)(T) * 8192; \
    const bf16_t* sb = W1Slab + (size_t)(T) * 8192; \
    _Pragma("unroll") \
    for (int p = 0; p < 4; ++p) { \
        const int off = p * 2048 + wid * 512; \
        __builtin_amdgcn_global_load_lds(AS_GLOBAL(sa + off + lane * 8), AS_LDS(&Alds[BUF][off]), 16, 0, 0); \
        __builtin_amdgcn_global_load_lds(AS_GLOBAL(sb + off + lane * 8), AS_LDS(&Blds[BUF][off]), 16, 0, 0); \
    } }

#define COMPUTE(BUF) { \
    _Pragma("unroll") \
    for (int kh = 0; kh < 2; ++kh) { \
        bf16x8 af[4], bfr[4]; \
        _Pragma("unroll") \
        for (int mf = 0; mf < 4; ++mf) { \
            const int r = wm * 64 + mf * 16 + lr; \
            af[mf] = *(const bf16x8*)&Alds[BUF][r * 64 + (((kh << 2) | lg) ^ (r & 7)) * 8]; \
        } \
        _Pragma("unroll") \
        for (int nf = 0; nf < 4; ++nf) { \
            const int f = wn * 64 + nf * 16 + lr; \
            bfr[nf] = *(const bf16x8*)&Blds[BUF][f * 64 + (((kh << 2) | lg) ^ (f & 7)) * 8]; \
        } \
        _Pragma("unroll") \
        for (int mf = 0; mf < 4; ++mf) \
            _Pragma("unroll") \
            for (int nf = 0; nf < 4; ++nf) \
                acc[mf][nf] = __builtin_amdgcn_mfma_f32_16x16x32_bf16(af[mf], bfr[nf], acc[mf][nf], 0, 0, 0); \
    } }

    // prologue
    STAGE(0, 0);
    __syncthreads();

    int cur = 0;
#pragma unroll 2
    for (int t = 0; t < 16; ++t) {
        if (t < 15) { STAGE(t + 1, cur ^ 1); }
        __builtin_amdgcn_sched_barrier(0);
        COMPUTE(cur);
        __syncthreads();   // drains t+1 staging (flew under compute)
        cur ^= 1;
    }
#undef STAGE
#undef COMPUTE

    // epilogue: exact gelu + weighted token-reduce
    float gcol[4] = {0.f, 0.f, 0.f, 0.f};
#pragma unroll
    for (int nf = 0; nf < 4; ++nf) {
        const float bb = b1_s[wn * 64 + nf * 16 + lr];
#pragma unroll
        for (int mf = 0; mf < 4; ++mf) {
#pragma unroll
            for (int i = 0; i < 4; ++i) {
                const int row = wm * 64 + mf * 16 + lg * 4 + i;  // C/D: col=lane&15, row=(lane>>4)*4+i
                const float h  = acc[mf][nf][i] + bb;
                const float gl = 0.5f * h * (1.f + erff(h * 0.70710678118654752f));
                gcol[nf] += w_s[row] * gl;
            }
        }
    }
#pragma unroll
    for (int nf = 0; nf < 4; ++nf) {
        gcol[nf] += __shfl_xor(gcol[nf], 16);
        gcol[nf] += __shfl_xor(gcol[nf], 32);
    }
    if (lane < 16) {
#pragma unroll
        for (int nf = 0; nf < 4; ++nf) gred[wm][wn * 64 + nf * 16 + lane] = gcol[nf];
    }
    __syncthreads();
    if (tid < 128) {
        const float sum = gred[0][tid] + gred[1][tid];
        gpart[(size_t)(e * CH_MAX + chunk) * F_DIM + ftile * 128 + tid] = sum;
    }
}

// ---------------- kernel 7: reduce chunk partials -> g[e][F] ----------------
__global__ __launch_bounds__(256) void k_redg(const float* __restrict__ gpart,
    const int* __restrict__ counts, float* __restrict__ g)
{
    const int e = blockIdx.y;
    const int f = blockIdx.x * 256 + threadIdx.x;
    const int nch = (counts[e] + CH_ROWS - 1) / CH_ROWS;
    float s = 0.f;
    for (int c = 0; c < nch; ++c)
        s += gpart[(size_t)(e * CH_MAX + c) * F_DIM + f];
    g[(size_t)e * F_DIM + f] = s;
}

// ---------------- kernel 8: W2 GEMV partials ----------------
__global__ __launch_bounds__(256) void k_out1(const float* __restrict__ g,
    const float* __restrict__ W2, float* __restrict__ p2)
{
    const int fc = blockIdx.x;
    const int e  = blockIdx.y;
    const int tid = threadIdx.x;
    __shared__ float gs[128];
    if (tid < 128) gs[tid] = g[(size_t)e * F_DIM + fc * 128 + tid];
    __syncthreads();
    const float* W2p = W2 + (size_t)e * F_DIM * H_DIM + (size_t)fc * 128 * H_DIM;
    float ax = 0.f, ay = 0.f, az = 0.f, aw = 0.f;
#pragma unroll 8
    for (int f = 0; f < 128; ++f) {
        const float gv = gs[f];
        const float4 wv = *(const float4*)(W2p + (size_t)f * H_DIM + tid * 4);
        ax += gv * wv.x; ay += gv * wv.y; az += gv * wv.z; aw += gv * wv.w;
    }
    float4 st; st.x = ax; st.y = ay; st.z = az; st.w = aw;
    *(float4*)(p2 + (size_t)(e * 32 + fc) * H_DIM + tid * 4) = st;
}

// ---------------- kernel 9: final reduce + bias + normalize ----------------
__global__ __launch_bounds__(256) void k_out2(const float* __restrict__ p2,
    const float* __restrict__ sumw, const float* __restrict__ b2, float* __restrict__ out)
{
    const int tid = threadIdx.x;
    const int hh  = tid & 31;
    const int seg = tid >> 5;
    const int h   = blockIdx.x * 32 + hh;
    float s = 0.f;
    for (int j = 0; j < 64; ++j)
        s += p2[(size_t)(seg * 64 + j) * H_DIM + h];
    __shared__ float red[8][33];
    red[seg][hh] = s;
    __syncthreads();
    if (tid < 32) {
        const int h2 = blockIdx.x * 32 + tid;
        float tot = 0.f;
#pragma unroll
        for (int q = 0; q < 8; ++q) tot += red[q][tid];
        float tw = 0.f, bias = 0.f;
#pragma unroll
        for (int e = 0; e < E_NUM; ++e) { tw += sumw[e]; bias += sumw[e] * b2[e * H_DIM + h2]; }
        out[h2] = (tot + bias) / tw;
    }
}

// ---------------- launch ----------------
extern "C" void kernel_launch(void* const* d_in, const int* in_sizes, int n_in,
                              void* d_out, int out_size, void* d_ws, size_t ws_size,
                              hipStream_t stream) {
    const float* x  = (const float*)d_in[0];
    const float* Wg = (const float*)d_in[1];
    const float* bg = (const float*)d_in[2];
    const float* W1 = (const float*)d_in[3];
    const float* b1 = (const float*)d_in[4];
    const float* W2 = (const float*)d_in[5];
    const float* b2 = (const float*)d_in[6];
    float* out = (float*)d_out;

    char* ws = (char*)d_ws;
    int*    e0     = (int*)(ws + WS_E0);
    int*    e1     = (int*)(ws + WS_E1);
    float*  w0     = (float*)(ws + WS_W0);
    float*  w1     = (float*)(ws + WS_W1);
    int*    counts = (int*)(ws + WS_COUNTS);
    float*  sumw   = (float*)(ws + WS_SUMW);
    int*    xoff   = (int*)(ws + WS_XOFF);
    int*    lidx   = (int*)(ws + WS_LIDX);
    float*  lw     = (float*)(ws + WS_LW);
    float*  gpart  = (float*)(ws + WS_GPART);
    float*  g      = (float*)(ws + WS_G);
    float*  p2     = (float*)(ws + WS_P2);   // aliases gpart (safe: gpart dead after k_redg)
    bf16_t* Xe     = (bf16_t*)(ws + WS_XE);
    bf16_t* W1T    = (bf16_t*)(ws + WS_W1T);

    // expert group size bounded by available scratch for W1T
    int cap = 1;
    if (ws_size > (size_t)WS_W1T + (size_t)W1T_PER_E) {
        size_t c = (ws_size - (size_t)WS_W1T) / (size_t)W1T_PER_E;
        cap = (c >= 16) ? 16 : (int)c;
        if (cap < 1) cap = 1;
    }

    k_route<<<T_TOK, 64, 0, stream>>>(x, Wg, bg, e0, e1, w0, w1);
    k_lists<<<E_NUM, 64, 0, stream>>>(e0, e1, w0, w1, lidx, lw, counts, sumw);
    k_scan<<<1, 64, 0, stream>>>(counts, xoff);
    k_gather<<<dim3(CH_MAX * 2, E_NUM), 256, 0, stream>>>(x, lidx, counts, xoff, Xe);
    for (int eb = 0; eb < E_NUM; eb += cap) {
        const int gN = (E_NUM - eb < cap) ? (E_NUM - eb) : cap;
        k_w1t<<<dim3(16, 4, gN), 512, 0, stream>>>(W1, W1T, eb);
        k_expert<<<dim3(32, CH_MAX, gN), 256, 0, stream>>>(W1T, b1, Xe, lw, counts, xoff, gpart, eb);
    }
    k_redg<<<dim3(F_DIM / 256, E_NUM), 256, 0, stream>>>(gpart, counts, g);
    k_out1<<<dim3(32, E_NUM), 256, 0, stream>>>(g, W2, p2);
    k_out2<<<32, 256, 0, stream>>>(p2, sumw, b2, out);
}

// Round 6
// 367.352 us; speedup vs baseline: 1.0006x; 1.0006x over previous
//
#include <hip/hip_runtime.h>
#include <hip/hip_bf16.h>
#include <math.h>

// ---------------- types ----------------
typedef __bf16 bf16_t;
typedef __bf16 bf16x4 __attribute__((ext_vector_type(4)));
typedef __bf16 bf16x8 __attribute__((ext_vector_type(8)));
typedef float  f32x4  __attribute__((ext_vector_type(4)));

#define T_TOK 4096
#define H_DIM 1024
#define E_NUM 16
#define F_DIM 4096
#define CH_ROWS 128   // tokens per chunk-block (M tile)
#define CH_MAX  32    // max chunks per expert

// ---------------- workspace layout (bytes) ----------------
#define WS_E0     0            // int[4096]
#define WS_E1     16384        // int[4096]
#define WS_W0     32768        // float[4096]
#define WS_W1     49152        // float[4096]
#define WS_COUNTS 65536        // int[16]
#define WS_SUMW   65664        // float[16]
#define WS_XOFF   65792        // int[16]
#define WS_LIDX   131072       // int[16][4096]
#define WS_LW     393216       // float[16][4096]
#define WS_GPART  655360       // float[16][32][4096]  (8 MB)
#define WS_P2     655360       // float[512][1024] (2 MB) ALIASES gpart (dead after k_redg)
#define WS_G      9043968      // float[16][4096]
#define WS_XE     9306112      // bf16[80 rowblk][16 kt][128 row][64 k] (20 MB), tiled+swizzled
#define WS_W1T    30277632     // bf16 [g][32 ft][16 kt][128 f][64 k], up to 128 MB
#define W1T_PER_E 8388608      // 8 MB per expert

#define AS_GLOBAL(p) ((const __attribute__((address_space(1))) void*)(p))
#define AS_LDS(p)    ((__attribute__((address_space(3))) void*)(p))

// ---------------- kernel 1: routing (scores + top2 + softmax) ----------------
__global__ __launch_bounds__(64) void k_route(const float* __restrict__ x,
    const float* __restrict__ Wg, const float* __restrict__ bg,
    int* __restrict__ e0, int* __restrict__ e1,
    float* __restrict__ w0, float* __restrict__ w1)
{
    const int t = blockIdx.x;
    const int lane = threadIdx.x;
    const float* xr = x + (size_t)t * H_DIM;

    float s[E_NUM];
#pragma unroll
    for (int e = 0; e < E_NUM; ++e) s[e] = 0.f;

#pragma unroll
    for (int i = 0; i < 16; ++i) {
        const int h = i * 64 + lane;
        const float xv = xr[h];
        const float4* wr = (const float4*)(Wg + (size_t)h * E_NUM);
        float4 q0 = wr[0], q1 = wr[1], q2 = wr[2], q3 = wr[3];
        s[0] += xv*q0.x;  s[1] += xv*q0.y;  s[2] += xv*q0.z;  s[3] += xv*q0.w;
        s[4] += xv*q1.x;  s[5] += xv*q1.y;  s[6] += xv*q1.z;  s[7] += xv*q1.w;
        s[8] += xv*q2.x;  s[9] += xv*q2.y;  s[10]+= xv*q2.z;  s[11]+= xv*q2.w;
        s[12]+= xv*q3.x;  s[13]+= xv*q3.y;  s[14]+= xv*q3.z;  s[15]+= xv*q3.w;
    }
#pragma unroll
    for (int off = 32; off >= 1; off >>= 1) {
#pragma unroll
        for (int e = 0; e < E_NUM; ++e) s[e] += __shfl_xor(s[e], off);
    }
    if (lane == 0) {
#pragma unroll
        for (int e = 0; e < E_NUM; ++e) s[e] += bg[e];
        float b1v = -3e38f; int i1 = 0;
#pragma unroll
        for (int e = 0; e < E_NUM; ++e) { if (s[e] > b1v) { b1v = s[e]; i1 = e; } }
        float b2v = -3e38f; int i2 = 0;
#pragma unroll
        for (int e = 0; e < E_NUM; ++e) { if (e != i1 && s[e] > b2v) { b2v = s[e]; i2 = e; } }
        const float ex  = expf(b2v - b1v);
        const float inv = 1.f / (1.f + ex);
        e0[t] = i1; e1[t] = i2;
        w0[t] = inv; w1[t] = ex * inv;
    }
}

// ---------------- kernel 2: per-expert token lists ----------------
__global__ __launch_bounds__(64) void k_lists(const int* __restrict__ e0, const int* __restrict__ e1,
    const float* __restrict__ w0, const float* __restrict__ w1,
    int* __restrict__ lidx, float* __restrict__ lw,
    int* __restrict__ counts, float* __restrict__ sumw)
{
    const int e = blockIdx.x;
    const int lane = threadIdx.x;
    int cnt = 0; float sw = 0.f;
    for (int base = 0; base < T_TOK; base += 64) {
        const int t = base + lane;
        const bool m0 = (e0[t] == e);
        const bool m1 = (e1[t] == e);
        const bool m  = m0 | m1;
        const unsigned long long bal = __ballot(m);
        const int pos = cnt + __popcll(bal & ((1ull << lane) - 1ull));
        if (m) {
            const float w = m0 ? w0[t] : w1[t];
            lidx[e * T_TOK + pos] = t;
            lw[e * T_TOK + pos]   = w;
            sw += w;
        }
        cnt += __popcll(bal);
    }
#pragma unroll
    for (int off = 32; off >= 1; off >>= 1) sw += __shfl_xor(sw, off);
    if (lane == 0) { counts[e] = cnt; sumw[e] = sw; }
}

// ---------------- kernel 3: exclusive scan of 128-padded counts ----------------
__global__ void k_scan(const int* __restrict__ counts, int* __restrict__ xoff) {
    if (threadIdx.x == 0) {
        int o = 0;
        for (int e = 0; e < E_NUM; ++e) { xoff[e] = o; o += (counts[e] + CH_ROWS - 1) & ~(CH_ROWS - 1); }
    }
}

// ---------------- kernel 4: gather + f32->bf16 into TILED swizzled Xe ----------------
// Xe layout: [rowblk][kt 16][row 128][slot 8][8 elems]; slot s holds logical k-chunk
// s ^ (row&7). A K-step slab (16 KB) is fully contiguous -> linear global_load_lds.
__global__ __launch_bounds__(256) void k_gather(const float* __restrict__ x,
    const int* __restrict__ lidx, const int* __restrict__ counts,
    const int* __restrict__ xoff, bf16_t* __restrict__ Xe)
{
    const int chunk = blockIdx.x >> 1;
    const int part  = blockIdx.x & 1;
    const int e = blockIdx.y;
    const int cnt = counts[e];
    const int start = chunk * CH_ROWS;
    if (chunk && start >= cnt) return;
    const int tid = threadIdx.x;
    const size_t base = ((size_t)(xoff[e] >> 7) + chunk) * 131072;  // rowblk slab elems

    for (int it = 0; it < 32; ++it) {
        const int u    = part * 8192 + it * 256 + tid;  // 16384 16B-chunk tasks
        const int kt   = u >> 10;
        const int wi   = u & 1023;
        const int rl   = wi >> 3;       // 0..127 local row
        const int c    = wi & 7;        // storage slot
        const int row  = start + rl;
        bf16x8 v8 = {};
        if (row < cnt) {
            const int tok = lidx[e * T_TOK + row];
            const int cp  = c ^ (rl & 7);              // logical chunk
            const int k   = kt * 64 + cp * 8;
            const float4 a = *(const float4*)(x + (size_t)tok * H_DIM + k);
            const float4 b = *(const float4*)(x + (size_t)tok * H_DIM + k + 4);
            v8[0]=(bf16_t)a.x; v8[1]=(bf16_t)a.y; v8[2]=(bf16_t)a.z; v8[3]=(bf16_t)a.w;
            v8[4]=(bf16_t)b.x; v8[5]=(bf16_t)b.y; v8[6]=(bf16_t)b.z; v8[7]=(bf16_t)b.w;
        }
        *(bf16x8*)(Xe + base + (size_t)kt * 8192 + rl * 64 + c * 8) = v8;
    }
}

// ---------------- kernel 5: W1 tile-transpose + cvt -> W1T bf16 (conflict-free) ----------------
// W1T layout: [ge][ft 32][kt 16][f 128][slot 8][8 k], slot s holds k-chunk s^(f&7).
// Block (kt, fq, ge): [64 k][1024 f] tile. LDS staged ALREADY slot-swizzled:
//   S(k, f) at k*1024 + ((f>>3)^(k&7))*8 + (f&7)   (bf16 elems)
// -> staging writes spread across banks; column gathers hit XOR-spread slots (<=2-way).
// Output rows are linear 128B runs forming contiguous 16 KB slabs per (ft,kt).
__global__ __launch_bounds__(512, 1) void k_w1t(const float* __restrict__ W1,
    bf16_t* __restrict__ W1T, int ebase)
{
    const int kt = blockIdx.x;   // 0..15
    const int fq = blockIdx.y;   // 0..3
    const int ge = blockIdx.z;
    const int e  = ebase + ge;
    const int tid = threadIdx.x;

    __shared__ bf16_t S[64 * 1024];   // 128 KB, swizzled

    const float* src = W1 + (size_t)e * H_DIM * F_DIM + (size_t)(kt * 64) * F_DIM + fq * 1024;

    // ---- load: 64 rows x 256 float4 (4KB contiguous per row), cvt, swizzled LDS store ----
    for (int it = 0; it < 32; ++it) {
        const int u  = it * 512 + tid;     // 16384 tasks
        const int k  = u >> 8;             // 0..63
        const int c4 = u & 255;            // float4 within row
        const int f  = c4 * 4;
        const float4 v = *(const float4*)(src + (size_t)k * F_DIM + c4 * 4);
        bf16x4 b4; b4[0]=(bf16_t)v.x; b4[1]=(bf16_t)v.y; b4[2]=(bf16_t)v.z; b4[3]=(bf16_t)v.w;
        const int slot = (f >> 3) ^ (k & 7);
        *(bf16x4*)&S[k * 1024 + slot * 8 + (f & 7)] = b4;
    }
    __syncthreads();

    // ---- emit: 1024 output rows (f), 2 per thread; each row = 64 bf16 (128 B linear) ----
#pragma unroll
    for (int ot = 0; ot < 2; ++ot) {
        const int f   = ot * 512 + tid;    // 0..1023
        const int ftl = f >> 7;            // 0..7
        const int fl  = f & 127;
        const int fsw = fl & 7;
        const int fh3 = f >> 3;
        bf16_t* dst = W1T + ((((size_t)ge * 32 + (fq * 8 + ftl)) * 16 + kt) * 8192) + fl * 64;
#pragma unroll
        for (int s = 0; s < 8; ++s) {
            const int c = s ^ fsw;         // logical k-chunk stored at slot s
            bf16x8 pk;
#pragma unroll
            for (int j = 0; j < 8; ++j) {
                const int k = c * 8 + j;
                pk[j] = S[k * 1024 + (fh3 ^ j) * 8 + (f & 7)];
            }
            *(bf16x8*)&dst[s * 8] = pk;
        }
    }
}

// ---------------- kernel 6: expert GEMM (all-linear staging, 2-phase) ----------------
// grid: (32 ft, CH_MAX, g). block 256 = 4 waves (2M x 2N); wave tile 64x64; BK=64.
// A and B both staged with linear 16KB-slab global_load_lds from pre-swizzled buffers.
__global__ __launch_bounds__(256, 2) void k_expert(
    const bf16_t* __restrict__ W1T, const float* __restrict__ b1,
    const bf16_t* __restrict__ Xe, const float* __restrict__ lw,
    const int* __restrict__ counts, const int* __restrict__ xoff,
    float* __restrict__ gpart, int ebase)
{
    const int ftile = blockIdx.x;          // 0..31
    const int chunk = blockIdx.y;          // 0..31
    const int ge    = blockIdx.z;
    const int e     = ebase + ge;
    const int cnt   = counts[e];
    const int start = chunk * CH_ROWS;
    if (chunk && start >= cnt) return;

    __shared__ __align__(16) bf16_t Alds[2][8192];  // 2 x 16 KB
    __shared__ __align__(16) bf16_t Blds[2][8192];  // 2 x 16 KB
    __shared__ float w_s[CH_ROWS];
    __shared__ float b1_s[128];
    __shared__ float gred[2][128];

    const int tid  = threadIdx.x;
    const int lane = tid & 63;
    const int wid  = tid >> 6;      // 4 waves
    const int wm   = wid & 1;       // M half (64 rows)
    const int wn   = wid >> 1;      // N half (64 f)
    const int lr   = lane & 15;
    const int lg   = lane >> 4;

    if (tid < CH_ROWS) {
        const int r = start + tid;
        w_s[tid] = (r < cnt) ? lw[e * T_TOK + r] : 0.f;
    }
    if (tid < 128) b1_s[tid] = b1[(size_t)e * F_DIM + ftile * 128 + tid];

    f32x4 acc[4][4];
#pragma unroll
    for (int i = 0; i < 4; ++i)
#pragma unroll
        for (int j = 0; j < 4; ++j)
#pragma unroll
            for (int q = 0; q < 4; ++q) acc[i][j][q] = 0.f;

    const bf16_t* XeSlab = Xe + ((size_t)(xoff[e] >> 7) + chunk) * 131072;
    const bf16_t* W1Slab = W1T + (((size_t)ge * 32 + ftile) * 16) * 8192;

#define STAGE(T, BUF) { \
    const bf16_t* sa = XeSlab + (size_t)(T) * 8192; \
    const bf16_t* sb = W1Slab + (size_t)(T) * 8192; \
    _Pragma("unroll") \
    for (int p = 0; p < 4; ++p) { \
        const int off = p * 2048 + wid * 512; \
        __builtin_amdgcn_global_load_lds(AS_GLOBAL(sa + off + lane * 8), AS_LDS(&Alds[BUF][off]), 16, 0, 0); \
        __builtin_amdgcn_global_load_lds(AS_GLOBAL(sb + off + lane * 8), AS_LDS(&Blds[BUF][off]), 16, 0, 0); \
    } }

#define COMPUTE(BUF) { \
    _Pragma("unroll") \
    for (int kh = 0; kh < 2; ++kh) { \
        bf16x8 af[4], bfr[4]; \
        _Pragma("unroll") \
        for (int mf = 0; mf < 4; ++mf) { \
            const int r = wm * 64 + mf * 16 + lr; \
            af[mf] = *(const bf16x8*)&Alds[BUF][r * 64 + (((kh << 2) | lg) ^ (r & 7)) * 8]; \
        } \
        _Pragma("unroll") \
        for (int nf = 0; nf < 4; ++nf) { \
            const int f = wn * 64 + nf * 16 + lr; \
            bfr[nf] = *(const bf16x8*)&Blds[BUF][f * 64 + (((kh << 2) | lg) ^ (f & 7)) * 8]; \
        } \
        _Pragma("unroll") \
        for (int mf = 0; mf < 4; ++mf) \
            _Pragma("unroll") \
            for (int nf = 0; nf < 4; ++nf) \
                acc[mf][nf] = __builtin_amdgcn_mfma_f32_16x16x32_bf16(af[mf], bfr[nf], acc[mf][nf], 0, 0, 0); \
    } }

    // prologue
    STAGE(0, 0);
    __syncthreads();

    int cur = 0;
#pragma unroll 2
    for (int t = 0; t < 16; ++t) {
        if (t < 15) { STAGE(t + 1, cur ^ 1); }
        __builtin_amdgcn_sched_barrier(0);
        COMPUTE(cur);
        __syncthreads();   // drains t+1 staging (flew under compute)
        cur ^= 1;
    }
#undef STAGE
#undef COMPUTE

    // epilogue: exact gelu + weighted token-reduce
    float gcol[4] = {0.f, 0.f, 0.f, 0.f};
#pragma unroll
    for (int nf = 0; nf < 4; ++nf) {
        const float bb = b1_s[wn * 64 + nf * 16 + lr];
#pragma unroll
        for (int mf = 0; mf < 4; ++mf) {
#pragma unroll
            for (int i = 0; i < 4; ++i) {
                const int row = wm * 64 + mf * 16 + lg * 4 + i;  // C/D: col=lane&15, row=(lane>>4)*4+i
                const float h  = acc[mf][nf][i] + bb;
                const float gl = 0.5f * h * (1.f + erff(h * 0.70710678118654752f));
                gcol[nf] += w_s[row] * gl;
            }
        }
    }
#pragma unroll
    for (int nf = 0; nf < 4; ++nf) {
        gcol[nf] += __shfl_xor(gcol[nf], 16);
        gcol[nf] += __shfl_xor(gcol[nf], 32);
    }
    if (lane < 16) {
#pragma unroll
        for (int nf = 0; nf < 4; ++nf) gred[wm][wn * 64 + nf * 16 + lane] = gcol[nf];
    }
    __syncthreads();
    if (tid < 128) {
        const float sum = gred[0][tid] + gred[1][tid];
        gpart[(size_t)(e * CH_MAX + chunk) * F_DIM + ftile * 128 + tid] = sum;
    }
}

// ---------------- kernel 7: reduce chunk partials -> g[e][F] ----------------
__global__ __launch_bounds__(256) void k_redg(const float* __restrict__ gpart,
    const int* __restrict__ counts, float* __restrict__ g)
{
    const int e = blockIdx.y;
    const int f = blockIdx.x * 256 + threadIdx.x;
    const int nch = (counts[e] + CH_ROWS - 1) / CH_ROWS;
    float s = 0.f;
    for (int c = 0; c < nch; ++c)
        s += gpart[(size_t)(e * CH_MAX + c) * F_DIM + f];
    g[(size_t)e * F_DIM + f] = s;
}

// ---------------- kernel 8: W2 GEMV partials ----------------
__global__ __launch_bounds__(256) void k_out1(const float* __restrict__ g,
    const float* __restrict__ W2, float* __restrict__ p2)
{
    const int fc = blockIdx.x;
    const int e  = blockIdx.y;
    const int tid = threadIdx.x;
    __shared__ float gs[128];
    if (tid < 128) gs[tid] = g[(size_t)e * F_DIM + fc * 128 + tid];
    __syncthreads();
    const float* W2p = W2 + (size_t)e * F_DIM * H_DIM + (size_t)fc * 128 * H_DIM;
    float ax = 0.f, ay = 0.f, az = 0.f, aw = 0.f;
#pragma unroll 8
    for (int f = 0; f < 128; ++f) {
        const float gv = gs[f];
        const float4 wv = *(const float4*)(W2p + (size_t)f * H_DIM + tid * 4);
        ax += gv * wv.x; ay += gv * wv.y; az += gv * wv.z; aw += gv * wv.w;
    }
    float4 st; st.x = ax; st.y = ay; st.z = az; st.w = aw;
    *(float4*)(p2 + (size_t)(e * 32 + fc) * H_DIM + tid * 4) = st;
}

// ---------------- kernel 9: final reduce + bias + normalize ----------------
__global__ __launch_bounds__(256) void k_out2(const float* __restrict__ p2,
    const float* __restrict__ sumw, const float* __restrict__ b2, float* __restrict__ out)
{
    const int tid = threadIdx.x;
    const int hh  = tid & 31;
    const int seg = tid >> 5;
    const int h   = blockIdx.x * 32 + hh;
    float s = 0.f;
    for (int j = 0; j < 64; ++j)
        s += p2[(size_t)(seg * 64 + j) * H_DIM + h];
    __shared__ float red[8][33];
    red[seg][hh] = s;
    __syncthreads();
    if (tid < 32) {
        const int h2 = blockIdx.x * 32 + tid;
        float tot = 0.f;
#pragma unroll
        for (int q = 0; q < 8; ++q) tot += red[q][tid];
        float tw = 0.f, bias = 0.f;
#pragma unroll
        for (int e = 0; e < E_NUM; ++e) { tw += sumw[e]; bias += sumw[e] * b2[e * H_DIM + h2]; }
        out[h2] = (tot + bias) / tw;
    }
}

// ---------------- launch ----------------
extern "C" void kernel_launch(void* const* d_in, const int* in_sizes, int n_in,
                              void* d_out, int out_size, void* d_ws, size_t ws_size,
                              hipStream_t stream) {
    const float* x  = (const float*)d_in[0];
    const float* Wg = (const float*)d_in[1];
    const float* bg = (const float*)d_in[2];
    const float* W1 = (const float*)d_in[3];
    const float* b1 = (const float*)d_in[4];
    const float* W2 = (const float*)d_in[5];
    const float* b2 = (const float*)d_in[6];
    float* out = (float*)d_out;

    char* ws = (char*)d_ws;
    int*    e0     = (int*)(ws + WS_E0);
    int*    e1     = (int*)(ws + WS_E1);
    float*  w0     = (float*)(ws + WS_W0);
    float*  w1     = (float*)(ws + WS_W1);
    int*    counts = (int*)(ws + WS_COUNTS);
    float*  sumw   = (float*)(ws + WS_SUMW);
    int*    xoff   = (int*)(ws + WS_XOFF);
    int*    lidx   = (int*)(ws + WS_LIDX);
    float*  lw     = (float*)(ws + WS_LW);
    float*  gpart  = (float*)(ws + WS_GPART);
    float*  g      = (float*)(ws + WS_G);
    float*  p2     = (float*)(ws + WS_P2);   // aliases gpart (safe: gpart dead after k_redg)
    bf16_t* Xe     = (bf16_t*)(ws + WS_XE);
    bf16_t* W1T    = (bf16_t*)(ws + WS_W1T);

    // expert group size bounded by available scratch for W1T
    int cap = 1;
    if (ws_size > (size_t)WS_W1T + (size_t)W1T_PER_E) {
        size_t c = (ws_size - (size_t)WS_W1T) / (size_t)W1T_PER_E;
        cap = (c >= 16) ? 16 : (int)c;
        if (cap < 1) cap = 1;
    }

    k_route<<<T_TOK, 64, 0, stream>>>(x, Wg, bg, e0, e1, w0, w1);
    k_lists<<<E_NUM, 64, 0, stream>>>(e0, e1, w0, w1, lidx, lw, counts, sumw);
    k_scan<<<1, 64, 0, stream>>>(counts, xoff);
    k_gather<<<dim3(CH_MAX * 2, E_NUM), 256, 0, stream>>>(x, lidx, counts, xoff, Xe);
    for (int eb = 0; eb < E_NUM; eb += cap) {
        const int gN = (E_NUM - eb < cap) ? (E_NUM - eb) : cap;
        k_w1t<<<dim3(16, 4, gN), 512, 0, stream>>>(W1, W1T, eb);
        k_expert<<<dim3(32, CH_MAX, gN), 256, 0, stream>>>(W1T, b1, Xe, lw, counts, xoff, gpart, eb);
    }
    k_redg<<<dim3(F_DIM / 256, E_NUM), 256, 0, stream>>>(gpart, counts, g);
    k_out1<<<dim3(32, E_NUM), 256, 0, stream>>>(g, W2, p2);
    k_out2<<<32, 256, 0, stream>>>(p2, sumw, b2, out);
}

// Round 7
// 314.282 us; speedup vs baseline: 1.1696x; 1.1689x over previous
//
#include <hip/hip_runtime.h>
#include <hip/hip_bf16.h>
#include <math.h>

// ---------------- types ----------------
typedef __bf16 bf16_t;
typedef __bf16 bf16x4 __attribute__((ext_vector_type(4)));
typedef __bf16 bf16x8 __attribute__((ext_vector_type(8)));
typedef float  f32x4  __attribute__((ext_vector_type(4)));

#define T_TOK 4096
#define H_DIM 1024
#define E_NUM 16
#define F_DIM 4096
#define CH_ROWS 128   // tokens per chunk-block (M tile)
#define CH_MAX  32    // max chunks per expert

// ---------------- workspace layout (bytes) ----------------
#define WS_E0     0            // int[4096]
#define WS_E1     16384        // int[4096]
#define WS_W0     32768        // float[4096]
#define WS_W1     49152        // float[4096]
#define WS_COUNTS 65536        // int[16]
#define WS_SUMW   65664        // float[16]
#define WS_XOFF   65792        // int[16]
#define WS_LIDX   131072       // int[16][4096]
#define WS_LW     393216       // float[16][4096]
#define WS_GPART  655360       // float[16][32][4096]  (8 MB)
#define WS_P2     655360       // float[512][1024] (2 MB) ALIASES gpart (dead after k_redg)
#define WS_G      9043968      // float[16][4096]
#define WS_XE     9306112      // bf16[80 rowblk][16 kt][128 row][64 k] (20 MB), tiled+swizzled
// total ~29.3 MB

#define AS_GLOBAL(p) ((const __attribute__((address_space(1))) void*)(p))
#define AS_LDS(p)    ((__attribute__((address_space(3))) void*)(p))

// ---------------- kernel 1: routing (scores + top2 + softmax) ----------------
// 4 tokens per 256-thread block (1 wave each)
__global__ __launch_bounds__(256) void k_route(const float* __restrict__ x,
    const float* __restrict__ Wg, const float* __restrict__ bg,
    int* __restrict__ e0, int* __restrict__ e1,
    float* __restrict__ w0, float* __restrict__ w1)
{
    const int t = blockIdx.x * 4 + (threadIdx.x >> 6);
    const int lane = threadIdx.x & 63;
    const float* xr = x + (size_t)t * H_DIM;

    float s[E_NUM];
#pragma unroll
    for (int e = 0; e < E_NUM; ++e) s[e] = 0.f;

#pragma unroll
    for (int i = 0; i < 16; ++i) {
        const int h = i * 64 + lane;
        const float xv = xr[h];
        const float4* wr = (const float4*)(Wg + (size_t)h * E_NUM);
        float4 q0 = wr[0], q1 = wr[1], q2 = wr[2], q3 = wr[3];
        s[0] += xv*q0.x;  s[1] += xv*q0.y;  s[2] += xv*q0.z;  s[3] += xv*q0.w;
        s[4] += xv*q1.x;  s[5] += xv*q1.y;  s[6] += xv*q1.z;  s[7] += xv*q1.w;
        s[8] += xv*q2.x;  s[9] += xv*q2.y;  s[10]+= xv*q2.z;  s[11]+= xv*q2.w;
        s[12]+= xv*q3.x;  s[13]+= xv*q3.y;  s[14]+= xv*q3.z;  s[15]+= xv*q3.w;
    }
#pragma unroll
    for (int off = 32; off >= 1; off >>= 1) {
#pragma unroll
        for (int e = 0; e < E_NUM; ++e) s[e] += __shfl_xor(s[e], off);
    }
    if (lane == 0) {
#pragma unroll
        for (int e = 0; e < E_NUM; ++e) s[e] += bg[e];
        float b1v = -3e38f; int i1 = 0;
#pragma unroll
        for (int e = 0; e < E_NUM; ++e) { if (s[e] > b1v) { b1v = s[e]; i1 = e; } }
        float b2v = -3e38f; int i2 = 0;
#pragma unroll
        for (int e = 0; e < E_NUM; ++e) { if (e != i1 && s[e] > b2v) { b2v = s[e]; i2 = e; } }
        const float ex  = expf(b2v - b1v);
        const float inv = 1.f / (1.f + ex);
        e0[t] = i1; e1[t] = i2;
        w0[t] = inv; w1[t] = ex * inv;
    }
}

// ---------------- kernel 2: per-expert token lists ----------------
__global__ __launch_bounds__(64) void k_lists(const int* __restrict__ e0, const int* __restrict__ e1,
    const float* __restrict__ w0, const float* __restrict__ w1,
    int* __restrict__ lidx, float* __restrict__ lw,
    int* __restrict__ counts, float* __restrict__ sumw)
{
    const int e = blockIdx.x;
    const int lane = threadIdx.x;
    int cnt = 0; float sw = 0.f;
    for (int base = 0; base < T_TOK; base += 64) {
        const int t = base + lane;
        const bool m0 = (e0[t] == e);
        const bool m1 = (e1[t] == e);
        const bool m  = m0 | m1;
        const unsigned long long bal = __ballot(m);
        const int pos = cnt + __popcll(bal & ((1ull << lane) - 1ull));
        if (m) {
            const float w = m0 ? w0[t] : w1[t];
            lidx[e * T_TOK + pos] = t;
            lw[e * T_TOK + pos]   = w;
            sw += w;
        }
        cnt += __popcll(bal);
    }
#pragma unroll
    for (int off = 32; off >= 1; off >>= 1) sw += __shfl_xor(sw, off);
    if (lane == 0) { counts[e] = cnt; sumw[e] = sw; }
}

// ---------------- kernel 3: exclusive scan of 128-padded counts ----------------
__global__ void k_scan(const int* __restrict__ counts, int* __restrict__ xoff) {
    if (threadIdx.x == 0) {
        int o = 0;
        for (int e = 0; e < E_NUM; ++e) { xoff[e] = o; o += (counts[e] + CH_ROWS - 1) & ~(CH_ROWS - 1); }
    }
}

// ---------------- kernel 4: gather + f32->bf16 into TILED swizzled Xe ----------------
// Xe layout: [rowblk][kt 16][row 128][slot 8][8 elems]; slot s holds logical k-chunk
// s ^ (row&7). A K-step slab (16 KB) is fully contiguous -> linear global_load_lds.
__global__ __launch_bounds__(256) void k_gather(const float* __restrict__ x,
    const int* __restrict__ lidx, const int* __restrict__ counts,
    const int* __restrict__ xoff, bf16_t* __restrict__ Xe)
{
    const int chunk = blockIdx.x >> 1;
    const int part  = blockIdx.x & 1;
    const int e = blockIdx.y;
    const int cnt = counts[e];
    const int start = chunk * CH_ROWS;
    if (chunk && start >= cnt) return;
    const int tid = threadIdx.x;
    const size_t base = ((size_t)(xoff[e] >> 7) + chunk) * 131072;  // rowblk slab elems

    for (int it = 0; it < 32; ++it) {
        const int u    = part * 8192 + it * 256 + tid;  // 16384 16B-chunk tasks
        const int kt   = u >> 10;
        const int wi   = u & 1023;
        const int rl   = wi >> 3;       // 0..127 local row
        const int c    = wi & 7;        // storage slot
        const int row  = start + rl;
        bf16x8 v8 = {};
        if (row < cnt) {
            const int tok = lidx[e * T_TOK + row];
            const int cp  = c ^ (rl & 7);              // logical chunk
            const int k   = kt * 64 + cp * 8;
            const float4 a = *(const float4*)(x + (size_t)tok * H_DIM + k);
            const float4 b = *(const float4*)(x + (size_t)tok * H_DIM + k + 4);
            v8[0]=(bf16_t)a.x; v8[1]=(bf16_t)a.y; v8[2]=(bf16_t)a.z; v8[3]=(bf16_t)a.w;
            v8[4]=(bf16_t)b.x; v8[5]=(bf16_t)b.y; v8[6]=(bf16_t)b.z; v8[7]=(bf16_t)b.w;
        }
        *(bf16x8*)(Xe + base + (size_t)kt * 8192 + rl * 64 + c * 8) = v8;
    }
}

// ---------------- kernel 5: expert GEMM (A linear from Xe, B reg-staged from W1) ----------------
// grid: (32 ft, CH_MAX, E). block 256 = 4 waves (2M x 2N); wave tile 64x64; BK=64.
// A: global_load_lds 16KB slabs from pre-swizzled Xe (dbuf, issued for t+1).
// B: 32 strided dword loads/thread from W1 (issued for t+1 early), cvt+XOR-slot
//    ds_write after COMPUTE (T14 split). All LDS writes/reads conflict-free:
//    layout [f 128][slot 8][8], slot = kslot ^ (f&7)  (128B rows = bank-neutral,
//    XOR spans slots 0..7 bijectively per 8-lane group).
__global__ __launch_bounds__(256, 2) void k_expert(
    const float* __restrict__ W1, const float* __restrict__ b1,
    const bf16_t* __restrict__ Xe, const float* __restrict__ lw,
    const int* __restrict__ counts, const int* __restrict__ xoff,
    float* __restrict__ gpart)
{
    const int ftile = blockIdx.x;          // 0..31
    const int chunk = blockIdx.y;          // 0..31
    const int e     = blockIdx.z;          // 0..15
    const int cnt   = counts[e];
    const int start = chunk * CH_ROWS;
    if (chunk && start >= cnt) return;

    __shared__ __align__(16) bf16_t Alds[2][8192];  // 2 x 16 KB
    __shared__ __align__(16) bf16_t Blds[2][8192];  // 2 x 16 KB
    __shared__ float w_s[CH_ROWS];
    __shared__ float b1_s[128];
    __shared__ float gred[2][128];

    const int tid  = threadIdx.x;
    const int lane = tid & 63;
    const int wid  = tid >> 6;      // 4 waves
    const int wm   = wid & 1;       // M half (64 rows)
    const int wn   = wid >> 1;      // N half (64 f)
    const int lr   = lane & 15;
    const int lg   = lane >> 4;

    if (tid < CH_ROWS) {
        const int r = start + tid;
        w_s[tid] = (r < cnt) ? lw[e * T_TOK + r] : 0.f;
    }
    if (tid < 128) b1_s[tid] = b1[(size_t)e * F_DIM + ftile * 128 + tid];

    f32x4 acc[4][4];
#pragma unroll
    for (int i = 0; i < 4; ++i)
#pragma unroll
        for (int j = 0; j < 4; ++j)
#pragma unroll
            for (int q = 0; q < 4; ++q) acc[i][j][q] = 0.f;

    const bf16_t* XeSlab = Xe + ((size_t)(xoff[e] >> 7) + chunk) * 131072;

    // B staging geometry: thread owns f column bf_ and k-half kh2 (32 rows)
    const int bf_ = tid & 127;
    const int kh2 = tid >> 7;
    const int fsw = bf_ & 7;
    const float* W1p = W1 + (size_t)e * H_DIM * F_DIM + (size_t)(kh2 * 32) * F_DIM
                       + (size_t)ftile * 128 + bf_;

    float bv[32];

#define ISSUE_A(T, BUF) { \
    _Pragma("unroll") \
    for (int p = 0; p < 4; ++p) { \
        const int off = p * 2048 + wid * 512; \
        __builtin_amdgcn_global_load_lds(AS_GLOBAL(XeSlab + (size_t)(T) * 8192 + off + lane * 8), \
            AS_LDS(&Alds[BUF][off]), 16, 0, 0); \
    } }

#define ISSUE_B(T) { \
    const float* wp = W1p + (size_t)(T) * 64 * F_DIM; \
    _Pragma("unroll") \
    for (int j = 0; j < 32; ++j) bv[j] = wp[(size_t)j * F_DIM]; }

#define WRITE_B(BUF) { \
    _Pragma("unroll") \
    for (int c = 0; c < 4; ++c) { \
        bf16x8 pk; \
        _Pragma("unroll") \
        for (int q = 0; q < 8; ++q) pk[q] = (bf16_t)bv[c * 8 + q]; \
        const int kslot = kh2 * 4 + c; \
        *(bf16x8*)&Blds[BUF][bf_ * 64 + (kslot ^ fsw) * 8] = pk; \
    } }

#define COMPUTE(BUF) { \
    _Pragma("unroll") \
    for (int kh = 0; kh < 2; ++kh) { \
        bf16x8 af[4], bfr[4]; \
        _Pragma("unroll") \
        for (int mf = 0; mf < 4; ++mf) { \
            const int r = wm * 64 + mf * 16 + lr; \
            af[mf] = *(const bf16x8*)&Alds[BUF][r * 64 + (((kh << 2) | lg) ^ (r & 7)) * 8]; \
        } \
        _Pragma("unroll") \
        for (int nf = 0; nf < 4; ++nf) { \
            const int f = wn * 64 + nf * 16 + lr; \
            bfr[nf] = *(const bf16x8*)&Blds[BUF][f * 64 + (((kh << 2) | lg) ^ (f & 7)) * 8]; \
        } \
        _Pragma("unroll") \
        for (int mf = 0; mf < 4; ++mf) \
            _Pragma("unroll") \
            for (int nf = 0; nf < 4; ++nf) \
                acc[mf][nf] = __builtin_amdgcn_mfma_f32_16x16x32_bf16(af[mf], bfr[nf], acc[mf][nf], 0, 0, 0); \
    } }

    // ---- prologue: stage K-step 0 ----
    ISSUE_B(0);
    ISSUE_A(0, 0);
    WRITE_B(0);                        // compiler waits vmcnt for bv
    __syncthreads();

    int cur = 0;
    for (int t = 0; t < 16; ++t) {
        // issue next tile's loads -> fly under this tile's compute
        if (t < 15) {
            ISSUE_B(t + 1);
            ISSUE_A(t + 1, cur ^ 1);
        }
        __builtin_amdgcn_sched_barrier(0);
        COMPUTE(cur);
        if (t < 15) WRITE_B(cur ^ 1);  // cvt + conflict-free LDS write (late)
        __syncthreads();               // drains A(t+1); orders B(t+1) writes
        cur ^= 1;
    }
#undef ISSUE_A
#undef ISSUE_B
#undef WRITE_B
#undef COMPUTE

    // ---- epilogue: exact gelu + weighted token-reduce ----
    float gcol[4] = {0.f, 0.f, 0.f, 0.f};
#pragma unroll
    for (int nf = 0; nf < 4; ++nf) {
        const float bb = b1_s[wn * 64 + nf * 16 + lr];
#pragma unroll
        for (int mf = 0; mf < 4; ++mf) {
#pragma unroll
            for (int i = 0; i < 4; ++i) {
                const int row = wm * 64 + mf * 16 + lg * 4 + i;  // C/D: col=lane&15, row=(lane>>4)*4+i
                const float h  = acc[mf][nf][i] + bb;
                const float gl = 0.5f * h * (1.f + erff(h * 0.70710678118654752f));
                gcol[nf] += w_s[row] * gl;
            }
        }
    }
#pragma unroll
    for (int nf = 0; nf < 4; ++nf) {
        gcol[nf] += __shfl_xor(gcol[nf], 16);
        gcol[nf] += __shfl_xor(gcol[nf], 32);
    }
    if (lane < 16) {
#pragma unroll
        for (int nf = 0; nf < 4; ++nf) gred[wm][wn * 64 + nf * 16 + lane] = gcol[nf];
    }
    __syncthreads();
    if (tid < 128) {
        const float sum = gred[0][tid] + gred[1][tid];
        gpart[(size_t)(e * CH_MAX + chunk) * F_DIM + ftile * 128 + tid] = sum;
    }
}

// ---------------- kernel 6: reduce chunk partials -> g[e][F] ----------------
__global__ __launch_bounds__(256) void k_redg(const float* __restrict__ gpart,
    const int* __restrict__ counts, float* __restrict__ g)
{
    const int e = blockIdx.y;
    const int f = blockIdx.x * 256 + threadIdx.x;
    const int nch = (counts[e] + CH_ROWS - 1) / CH_ROWS;
    float s = 0.f;
    for (int c = 0; c < nch; ++c)
        s += gpart[(size_t)(e * CH_MAX + c) * F_DIM + f];
    g[(size_t)e * F_DIM + f] = s;
}

// ---------------- kernel 7: W2 GEMV partials ----------------
__global__ __launch_bounds__(256) void k_out1(const float* __restrict__ g,
    const float* __restrict__ W2, float* __restrict__ p2)
{
    const int fc = blockIdx.x;
    const int e  = blockIdx.y;
    const int tid = threadIdx.x;
    __shared__ float gs[128];
    if (tid < 128) gs[tid] = g[(size_t)e * F_DIM + fc * 128 + tid];
    __syncthreads();
    const float* W2p = W2 + (size_t)e * F_DIM * H_DIM + (size_t)fc * 128 * H_DIM;
    float ax = 0.f, ay = 0.f, az = 0.f, aw = 0.f;
#pragma unroll 8
    for (int f = 0; f < 128; ++f) {
        const float gv = gs[f];
        const float4 wv = *(const float4*)(W2p + (size_t)f * H_DIM + tid * 4);
        ax += gv * wv.x; ay += gv * wv.y; az += gv * wv.z; aw += gv * wv.w;
    }
    float4 st; st.x = ax; st.y = ay; st.z = az; st.w = aw;
    *(float4*)(p2 + (size_t)(e * 32 + fc) * H_DIM + tid * 4) = st;
}

// ---------------- kernel 8: final reduce + bias + normalize ----------------
__global__ __launch_bounds__(256) void k_out2(const float* __restrict__ p2,
    const float* __restrict__ sumw, const float* __restrict__ b2, float* __restrict__ out)
{
    const int tid = threadIdx.x;
    const int hh  = tid & 31;
    const int seg = tid >> 5;
    const int h   = blockIdx.x * 32 + hh;
    float s = 0.f;
    for (int j = 0; j < 64; ++j)
        s += p2[(size_t)(seg * 64 + j) * H_DIM + h];
    __shared__ float red[8][33];
    red[seg][hh] = s;
    __syncthreads();
    if (tid < 32) {
        const int h2 = blockIdx.x * 32 + tid;
        float tot = 0.f;
#pragma unroll
        for (int q = 0; q < 8; ++q) tot += red[q][tid];
        float tw = 0.f, bias = 0.f;
#pragma unroll
        for (int e = 0; e < E_NUM; ++e) { tw += sumw[e]; bias += sumw[e] * b2[e * H_DIM + h2]; }
        out[h2] = (tot + bias) / tw;
    }
}

// ---------------- launch ----------------
extern "C" void kernel_launch(void* const* d_in, const int* in_sizes, int n_in,
                              void* d_out, int out_size, void* d_ws, size_t ws_size,
                              hipStream_t stream) {
    const float* x  = (const float*)d_in[0];
    const float* Wg = (const float*)d_in[1];
    const float* bg = (const float*)d_in[2];
    const float* W1 = (const float*)d_in[3];
    const float* b1 = (const float*)d_in[4];
    const float* W2 = (const float*)d_in[5];
    const float* b2 = (const float*)d_in[6];
    float* out = (float*)d_out;

    char* ws = (char*)d_ws;
    int*    e0     = (int*)(ws + WS_E0);
    int*    e1     = (int*)(ws + WS_E1);
    float*  w0     = (float*)(ws + WS_W0);
    float*  w1     = (float*)(ws + WS_W1);
    int*    counts = (int*)(ws + WS_COUNTS);
    float*  sumw   = (float*)(ws + WS_SUMW);
    int*    xoff   = (int*)(ws + WS_XOFF);
    int*    lidx   = (int*)(ws + WS_LIDX);
    float*  lw     = (float*)(ws + WS_LW);
    float*  gpart  = (float*)(ws + WS_GPART);
    float*  g      = (float*)(ws + WS_G);
    float*  p2     = (float*)(ws + WS_P2);   // aliases gpart (safe: gpart dead after k_redg)
    bf16_t* Xe     = (bf16_t*)(ws + WS_XE);

    k_route<<<T_TOK / 4, 256, 0, stream>>>(x, Wg, bg, e0, e1, w0, w1);
    k_lists<<<E_NUM, 64, 0, stream>>>(e0, e1, w0, w1, lidx, lw, counts, sumw);
    k_scan<<<1, 64, 0, stream>>>(counts, xoff);
    k_gather<<<dim3(CH_MAX * 2, E_NUM), 256, 0, stream>>>(x, lidx, counts, xoff, Xe);
    k_expert<<<dim3(32, CH_MAX, E_NUM), 256, 0, stream>>>(W1, b1, Xe, lw, counts, xoff, gpart);
    k_redg<<<dim3(F_DIM / 256, E_NUM), 256, 0, stream>>>(gpart, counts, g);
    k_out1<<<dim3(32, E_NUM), 256, 0, stream>>>(g, W2, p2);
    k_out2<<<32, 256, 0, stream>>>(p2, sumw, b2, out);
}